// Round 13
// baseline (1600.335 us; speedup 1.0000x reference)
//
#include <hip/hip_runtime.h>
#include <math.h>

// B=256, T=2048, H=150. Sequential GRU, relu'd hidden, scalar linear head.
// 1 block / batch element (256 blocks = 256 CUs), 512 threads.
//
// R25 = R24 (1571us: broadcast h-transport + rcp gates) re-decomposed from
// 8 chains to 4 chains (R12 geometry) to HALVE the P2 gather:
//   - wave w: chain q = w&3, idx = ((w>>2)<<6)+lane (0..127), rows
//     4idx..4idx+3, k-slots m=0..37 (k = 4m+q). Same 152 weight VGPRs,
//     same 76 pk ops/wave.
//   - P1 h-broadcast: 19 uniform ds_read_b64 (pairs h[8j+q],h[8j+4+q]...
//     i.e. slots 2j,2j+1), pipelined under MACs with counted lgkmcnt and
//     scratch-pair rotation in v80..v99 (interleaved re-issue; waits are
//     tail-robust: extras only make them stricter).
//   - P2 per gate: 4 partials -> 12 reads + 9 adds (depth 2) vs 24+21
//     (depth 3): ~70-100cy off the 3-wave serial phase. 2 stores (vs 4).
//   - Reduction tree ((q0+q1)+(q2+q3))+bhh and within-chain order =
//     R12's verified association -> absmax ~4.88e-4.
// Banks: stores 8B-stride (free); P2 reads 2-way (addr walks r mod 32);
// hb write (u&3)*40+(u>>2) 2-way; uniform reads broadcast (free).
// Ledger: h-transport R23 (-7%), rcp R24 (-5.4%); P1 batching +65% (R21);
// P2 spread +9/+15% (R13/R16); LDS atomics 6.6x (R19).

#define BB 256
#define TT 2048
#define HH 150
#define H3 450

typedef float fx2 __attribute__((ext_vector_type(2)));

// Clobber list for explicit weight registers v100..v251.
#define WCLOB \
  "v100","v101","v102","v103","v104","v105","v106","v107","v108","v109", \
  "v110","v111","v112","v113","v114","v115","v116","v117","v118","v119", \
  "v120","v121","v122","v123","v124","v125","v126","v127","v128","v129", \
  "v130","v131","v132","v133","v134","v135","v136","v137","v138","v139", \
  "v140","v141","v142","v143","v144","v145","v146","v147","v148","v149", \
  "v150","v151","v152","v153","v154","v155","v156","v157","v158","v159", \
  "v160","v161","v162","v163","v164","v165","v166","v167","v168","v169", \
  "v170","v171","v172","v173","v174","v175","v176","v177","v178","v179", \
  "v180","v181","v182","v183","v184","v185","v186","v187","v188","v189", \
  "v190","v191","v192","v193","v194","v195","v196","v197","v198","v199", \
  "v200","v201","v202","v203","v204","v205","v206","v207","v208","v209", \
  "v210","v211","v212","v213","v214","v215","v216","v217","v218","v219", \
  "v220","v221","v222","v223","v224","v225","v226","v227","v228","v229", \
  "v230","v231","v232","v233","v234","v235","v236","v237","v238","v239", \
  "v240","v241","v242","v243","v244","v245","v246","v247","v248","v249", \
  "v250","v251"

// h-broadcast scratch pairs v[80:81]..v[98:99] (rotated, 10 pairs live).
#define HCLOB \
  "v80","v81","v82","v83","v84","v85","v86","v87","v88","v89", \
  "v90","v91","v92","v93","v94","v95","v96","v97","v98","v99"

// Load one k-slot (slot m at byte offset 16*m) for all 4 rows.
// A pair (rows r0,r1) = v[100+2m:101+2m]; B pair (r2,r3) = v[176+2m].
#define LD4(vA0,vA1,vB0,vB1,OFF) \
  "global_load_dword v" #vA0 ", %[b0], off offset:" #OFF "\n\t" \
  "global_load_dword v" #vA1 ", %[b1], off offset:" #OFF "\n\t" \
  "global_load_dword v" #vB0 ", %[b2], off offset:" #OFF "\n\t" \
  "global_load_dword v" #vB1 ", %[b3], off offset:" #OFF "\n\t"

// pk_fma / pk_mul with broadcast from LOW or HIGH word of VGPR pair hp.
#define PKBL(hp, wp, acc) \
  "v_pk_fma_f32 " acc ", " hp ", " wp ", " acc " op_sel:[0,0,0] op_sel_hi:[0,1,1]\n\t"
#define PKBH(hp, wp, acc) \
  "v_pk_fma_f32 " acc ", " hp ", " wp ", " acc " op_sel:[1,0,0] op_sel_hi:[1,1,1]\n\t"
#define PKML(hp, wp, acc) \
  "v_pk_mul_f32 " acc ", " hp ", " wp " op_sel:[0,0] op_sel_hi:[0,1]\n\t"

// Consume one k-slot (2 pk ops: A->a01, B->a23).
#define C0(P, A, B)  PKML(P, A, "%[a01]") PKML(P, B, "%[a23]")
#define CPL(P, A, B) PKBL(P, A, "%[a01]") PKBL(P, B, "%[a23]")
#define CPH(P, A, B) PKBH(P, A, "%[a01]") PKBH(P, B, "%[a23]")

__global__ __launch_bounds__(512, 2) void gru_seq_kernel(
    const float* __restrict__ input,   // [B,T]
    const float* __restrict__ W_ih,    // [450,1]
    const float* __restrict__ W_hh,    // [450,150]
    const float* __restrict__ b_ih,    // [450]
    const float* __restrict__ b_hh,    // [450]
    const float* __restrict__ W_lin,   // [1,150]
    const float* __restrict__ b_lin,   // [1]
    float* __restrict__ out)           // [B,T]
{
    const int b    = blockIdx.x;
    const int tid  = threadIdx.x;
    const int lane = tid & 63;
    const int wid  = tid >> 6;               // 0..7
    const int q    = wid & 3;                // chain (k mod 4)
    const int idx  = ((wid >> 2) << 6) + lane;   // 0..127

    __shared__ float xrow[TT];         // 8 KB input row
    __shared__ float PPf[2080];        // 8.3 KB partials:
                                       // float = c2*1040 + q*260 + g*2 + c
                                       // (c2 = row-pair, g = idx, c = r&1)
    __shared__ __align__(16) float hb[160];  // h: hb[(u&3)*40 + (u>>2)]
    __shared__ float yout[TT];         // 8 KB y buffer

    // ---- prologue -------------------------------------------------------
    ((float4*)xrow)[tid] = ((const float4*)(input + (size_t)b * TT))[tid];
    if (tid < 160) hb[tid] = 0.f;

    // Rows 4idx..4idx+3. Row 450 = W_lin (y-row). Row >=451: clamp to 449
    // (junk partials stored at g=113..127 / comp never read).
    const int r0 = 4 * idx;
#define ROWP(r) ((r) == H3 ? W_lin : W_hh + ((r) < H3 ? (r) : (H3 - 1)) * HH)
    const float* b0 = ROWP(r0)     + q;   // chain q: element k = 4m+q
    const float* b1 = ROWP(r0 + 1) + q;
    const float* b2 = ROWP(r0 + 2) + q;
    const float* b3 = ROWP(r0 + 3) + q;

    // m = 0..36 into explicit regs (slot m at byte offset 16m).
    asm volatile(
        LD4(100,101,176,177,0)    LD4(102,103,178,179,16)
        LD4(104,105,180,181,32)   LD4(106,107,182,183,48)
        LD4(108,109,184,185,64)   LD4(110,111,186,187,80)
        LD4(112,113,188,189,96)   LD4(114,115,190,191,112)
        LD4(116,117,192,193,128)  LD4(118,119,194,195,144)
        LD4(120,121,196,197,160)  LD4(122,123,198,199,176)
        LD4(124,125,200,201,192)  LD4(126,127,202,203,208)
        LD4(128,129,204,205,224)  LD4(130,131,206,207,240)
        LD4(132,133,208,209,256)  LD4(134,135,210,211,272)
        LD4(136,137,212,213,288)  LD4(138,139,214,215,304)
        LD4(140,141,216,217,320)  LD4(142,143,218,219,336)
        LD4(144,145,220,221,352)  LD4(146,147,222,223,368)
        LD4(148,149,224,225,384)  LD4(150,151,226,227,400)
        LD4(152,153,228,229,416)  LD4(154,155,230,231,432)
        LD4(156,157,232,233,448)  LD4(158,159,234,235,464)
        LD4(160,161,236,237,480)  LD4(162,163,238,239,496)
        LD4(164,165,240,241,512)  LD4(166,167,242,243,528)
        LD4(168,169,244,245,544)  LD4(170,171,246,247,560)
        LD4(172,173,248,249,576)
        "s_waitcnt vmcnt(0)\n\t"
        :
        : [b0] "v"(b0), [b1] "v"(b1), [b2] "v"(b2), [b3] "v"(b3)
        : WCLOB, "memory");
    // m = 37: k = 148+q. Real for q<2; for q>=2 h[150..151]=0 forever
    // (hb slots never written), so load in-bounds junk (k=144+q).
    {
        const int t37 = (q < 2) ? 148 : 144;
        float w0 = b0[t37], w1 = b1[t37], w2 = b2[t37], w3 = b3[t37];
        asm volatile(
            "v_mov_b32 v174, %0\n\tv_mov_b32 v175, %1\n\t"
            "v_mov_b32 v250, %2\n\tv_mov_b32 v251, %3\n\t"
            :: "v"(w0), "v"(w1), "v"(w2), "v"(w3)
            : "v174","v175","v250","v251");
    }

    // Phase-2 constants (threads 0..149) -- gate math per R24 (rcp).
    float wih_r = 0.f, wih_z = 0.f, wih_n = 0.f;
    float bih_r = 0.f, bih_z = 0.f, bih_n = 0.f;
    float bhh_r = 0.f, bhh_z = 0.f, bhh_n = 0.f;
    if (tid < HH) {
        wih_r = W_ih[tid];          bih_r = b_ih[tid];          bhh_r = b_hh[tid];
        wih_z = W_ih[HH + tid];     bih_z = b_ih[HH + tid];     bhh_z = b_hh[HH + tid];
        wih_n = W_ih[2 * HH + tid]; bih_n = b_ih[2 * HH + tid]; bhh_n = b_hh[2 * HH + tid];
    }
    const float blin = b_lin[0];
    float hreg = 0.f;
    float* outb = out + (size_t)b * TT;
    // Store pointer: 2 float2 (8B lane stride = 2-way alias = free).
    float2* st = (float2*)PPf + q * 130 + idx;
    // Wave-uniform LDS byte address of this wave's h chain (hb + q*160B).
    const unsigned hva = (unsigned)(size_t)(&hb[q * 40]);
    // Phase-2 read indices: fidx(r) = ((r&3)>>1)*1040 + (r>>2)*2 + (r&1);
    // chain offset +260 floats. Banks walk r mod 32 -> 2-way (free).
    int ir = 0, iz = 0, in_ = 0;
    if (tid < HH) {
        int r;
        r = tid;        ir  = ((r & 3) >> 1) * 1040 + ((r >> 2) << 1) + (r & 1);
        r = HH + tid;   iz  = ((r & 3) >> 1) * 1040 + ((r >> 2) << 1) + (r & 1);
        r = 2*HH + tid; in_ = ((r & 3) >> 1) * 1040 + ((r >> 2) << 1) + (r & 1);
    }
    const int iy = 1040 + 112 * 2;      // row 450: c2=1, g=112, c=0 -> 1264

    __syncthreads();

    // ---- recurrence -----------------------------------------------------
    // Iteration t dots h_{t-1}; row 450 gives y_{t-1}. Extra iteration
    // t==TT supplies y_{TT-1}; its h-update is guarded off.
    for (int t = 0; t <= TT; ++t) {
        // phase 1: chain q of rows 4idx..4idx+3. 19 uniform ds_read_b64
        // broadcasts (pair j = slots 2j,2j+1), scratch rotated in
        // v80..v99, counted lgkmcnt (tail-robust), pipelined under MACs.
        fx2 a01, a23;                  // first-touched by PKML in slot 0
        asm volatile(
            "ds_read_b64 v[80:81], %[va] offset:0\n\t"    // p0
            "ds_read_b64 v[82:83], %[va] offset:8\n\t"    // p1
            "ds_read_b64 v[84:85], %[va] offset:16\n\t"   // p2
            "ds_read_b64 v[86:87], %[va] offset:24\n\t"   // p3
            "ds_read_b64 v[88:89], %[va] offset:32\n\t"   // p4
            "ds_read_b64 v[90:91], %[va] offset:40\n\t"   // p5
            "ds_read_b64 v[92:93], %[va] offset:48\n\t"   // p6
            "ds_read_b64 v[94:95], %[va] offset:56\n\t"   // p7
            "ds_read_b64 v[96:97], %[va] offset:64\n\t"   // p8
            "ds_read_b64 v[98:99], %[va] offset:72\n\t"   // p9
            "s_waitcnt lgkmcnt(8)\n\t"                    // p0,p1 landed
            C0 ("v[80:81]", "v[100:101]", "v[176:177]")   // slot 0
            CPH("v[80:81]", "v[102:103]", "v[178:179]")   // slot 1
            CPL("v[82:83]", "v[104:105]", "v[180:181]")   // slot 2
            CPH("v[82:83]", "v[106:107]", "v[182:183]")   // slot 3
            "s_waitcnt lgkmcnt(6)\n\t"                    // p2,p3
            CPL("v[84:85]", "v[108:109]", "v[184:185]")   // slot 4
            CPH("v[84:85]", "v[110:111]", "v[186:187]")   // slot 5
            CPL("v[86:87]", "v[112:113]", "v[188:189]")   // slot 6
            CPH("v[86:87]", "v[114:115]", "v[190:191]")   // slot 7
            "ds_read_b64 v[80:81], %[va] offset:80\n\t"   // p10
            "ds_read_b64 v[82:83], %[va] offset:88\n\t"   // p11
            "ds_read_b64 v[84:85], %[va] offset:96\n\t"   // p12
            "ds_read_b64 v[86:87], %[va] offset:104\n\t"  // p13
            "s_waitcnt lgkmcnt(8)\n\t"                    // p4,p5
            CPL("v[88:89]", "v[116:117]", "v[192:193]")   // slot 8
            CPH("v[88:89]", "v[118:119]", "v[194:195]")   // slot 9
            CPL("v[90:91]", "v[120:121]", "v[196:197]")   // slot 10
            CPH("v[90:91]", "v[122:123]", "v[198:199]")   // slot 11
            "s_waitcnt lgkmcnt(6)\n\t"                    // p6,p7
            CPL("v[92:93]", "v[124:125]", "v[200:201]")   // slot 12
            CPH("v[92:93]", "v[126:127]", "v[202:203]")   // slot 13
            CPL("v[94:95]", "v[128:129]", "v[204:205]")   // slot 14
            CPH("v[94:95]", "v[130:131]", "v[206:207]")   // slot 15
            "ds_read_b64 v[88:89], %[va] offset:112\n\t"  // p14
            "ds_read_b64 v[90:91], %[va] offset:120\n\t"  // p15
            "ds_read_b64 v[92:93], %[va] offset:128\n\t"  // p16
            "ds_read_b64 v[94:95], %[va] offset:136\n\t"  // p17
            "s_waitcnt lgkmcnt(8)\n\t"                    // p8,p9
            CPL("v[96:97]", "v[132:133]", "v[208:209]")   // slot 16
            CPH("v[96:97]", "v[134:135]", "v[210:211]")   // slot 17
            CPL("v[98:99]", "v[136:137]", "v[212:213]")   // slot 18
            CPH("v[98:99]", "v[138:139]", "v[214:215]")   // slot 19
            "ds_read_b64 v[96:97], %[va] offset:144\n\t"  // p18
            "s_waitcnt lgkmcnt(7)\n\t"                    // p10,p11
            CPL("v[80:81]", "v[140:141]", "v[216:217]")   // slot 20
            CPH("v[80:81]", "v[142:143]", "v[218:219]")   // slot 21
            CPL("v[82:83]", "v[144:145]", "v[220:221]")   // slot 22
            CPH("v[82:83]", "v[146:147]", "v[222:223]")   // slot 23
            "s_waitcnt lgkmcnt(5)\n\t"                    // p12,p13
            CPL("v[84:85]", "v[148:149]", "v[224:225]")   // slot 24
            CPH("v[84:85]", "v[150:151]", "v[226:227]")   // slot 25
            CPL("v[86:87]", "v[152:153]", "v[228:229]")   // slot 26
            CPH("v[86:87]", "v[154:155]", "v[230:231]")   // slot 27
            "s_waitcnt lgkmcnt(3)\n\t"                    // p14,p15
            CPL("v[88:89]", "v[156:157]", "v[232:233]")   // slot 28
            CPH("v[88:89]", "v[158:159]", "v[234:235]")   // slot 29
            CPL("v[90:91]", "v[160:161]", "v[236:237]")   // slot 30
            CPH("v[90:91]", "v[162:163]", "v[238:239]")   // slot 31
            "s_waitcnt lgkmcnt(1)\n\t"                    // p16,p17
            CPL("v[92:93]", "v[164:165]", "v[240:241]")   // slot 32
            CPH("v[92:93]", "v[166:167]", "v[242:243]")   // slot 33
            CPL("v[94:95]", "v[168:169]", "v[244:245]")   // slot 34
            CPH("v[94:95]", "v[170:171]", "v[246:247]")   // slot 35
            "s_waitcnt lgkmcnt(0)\n\t"                    // p18
            CPL("v[96:97]", "v[172:173]", "v[248:249]")   // slot 36
            CPH("v[96:97]", "v[174:175]", "v[250:251]")   // slot 37
            : [a01] "=&v"(a01), [a23] "=&v"(a23)
            : [va] "v"(hva)
            : HCLOB, WCLOB);
        // Two conflict-free b64 stores (8B lane stride).
        float2 s01; s01.x = a01.x; s01.y = a01.y;
        float2 s23; s23.x = a23.x; s23.y = a23.y;
        st[0]   = s01;
        st[520] = s23;
        __syncthreads();

        // phase 2: gates + hidden update (threads 0..149), skipped at t==TT.
        // pre_row = ((q0+q1)+(q2+q3)) + bhh -- 4 partials, depth-2 tree.
        if (t < TT && tid < HH) {
            float x  = xrow[t];
            float pr = ((PPf[ir]        + PPf[ir + 260])
                      + (PPf[ir + 520]  + PPf[ir + 780]))  + bhh_r;
            float pz = ((PPf[iz]        + PPf[iz + 260])
                      + (PPf[iz + 520]  + PPf[iz + 780]))  + bhh_z;
            float pn = ((PPf[in_]       + PPf[in_ + 260])
                      + (PPf[in_ + 520] + PPf[in_ + 780])) + bhh_n;
            float gr = fmaf(x, wih_r, bih_r) + pr;
            float gz = fmaf(x, wih_z, bih_z) + pz;
            float r  = __builtin_amdgcn_rcpf(1.f + __expf(-gr));
            float z  = __builtin_amdgcn_rcpf(1.f + __expf(-gz));
            float ta = fmaf(x, wih_n, bih_n) + r * pn;
            ta = fminf(fmaxf(ta, -15.f), 15.f);
            float e  = __expf(2.f * ta);
            float n  = (e - 1.f) * __builtin_amdgcn_rcpf(e + 1.f);  // tanh
            float hnew = fmaf(z, hreg - n, n);       // (1-z)*n + z*h
            hnew = fmaxf(hnew, 0.f);                 // relu
            hreg = hnew;
            hb[(tid & 3) * 40 + (tid >> 2)] = hnew;  // 2-way write alias
        }
        // y_{t-1} from phase-1 row 450 (same depth-2 tree), wave 7.
        if (t > 0 && tid == H3) {
            yout[t - 1] = ((PPf[iy]       + PPf[iy + 260])
                         + (PPf[iy + 520] + PPf[iy + 780])) + blin;
        }
        __syncthreads();
    }

    // ---- epilogue: coalesced y dump (the loop's only global write) -------
    ((float4*)outb)[tid] = ((const float4*)yout)[tid];
}

extern "C" void kernel_launch(void* const* d_in, const int* in_sizes, int n_in,
                              void* d_out, int out_size, void* d_ws, size_t ws_size,
                              hipStream_t stream) {
    const float* input = (const float*)d_in[0];
    const float* W_ih  = (const float*)d_in[1];
    const float* W_hh  = (const float*)d_in[2];
    const float* b_ih  = (const float*)d_in[3];
    const float* b_hh  = (const float*)d_in[4];
    const float* W_lin = (const float*)d_in[5];
    const float* b_lin = (const float*)d_in[6];
    float* out = (float*)d_out;

    gru_seq_kernel<<<dim3(BB), dim3(512), 0, stream>>>(
        input, W_ih, W_hh, b_ih, b_hh, W_lin, b_lin, out);
}

// Round 14
// 1575.685 us; speedup vs baseline: 1.0156x; 1.0156x over previous
//
#include <hip/hip_runtime.h>
#include <math.h>

// B=256, T=2048, H=150. Sequential GRU, relu'd hidden, scalar linear head.
// 1 block / batch element (256 blocks = 256 CUs), 512 threads.
//
// R26 = R24 verbatim (verified best: 1571us, absmax 4.88e-4).
// R25 (4-chain, halved P2 gather) regressed +1.9%: conflicts fell 3.6e7->
// 8.4e6 as predicted but P1's broadcast chain lengthened (19 reads + 9
// waits vs 10 + 5) -- P1 broadcast-chain length costs more than P2 tree
// depth saves. 8-chain is the measured optimum of that trade. Reverted.
//
// Structure: 8-chain P1 (wave w = chain k%8, lane l = rows 8l..8l+7),
// h-broadcast via 10 uniform-address ds_read_b64 + op_sel (R23, -7%),
// rcp-based gates (R24, -5.4%), stride-68/72 bank-free LDS geometry
// (R17), two barriers, P2 concentrated on tid<150.
// Ledger (all measured): chain split 4 vs 8 mapped (R25/R24); P1 batching
// +65% (R21); P2 spread +9/+15% (R13/R16); LDS atomics 6.6x (R19); issue
// micros neutral (R15/R18); conflicts at 2-way structural floor.

#define BB 256
#define TT 2048
#define HH 150
#define H3 450

typedef float fx2 __attribute__((ext_vector_type(2)));

// Clobber list for explicit weight registers v100..v251.
#define WCLOB \
  "v100","v101","v102","v103","v104","v105","v106","v107","v108","v109", \
  "v110","v111","v112","v113","v114","v115","v116","v117","v118","v119", \
  "v120","v121","v122","v123","v124","v125","v126","v127","v128","v129", \
  "v130","v131","v132","v133","v134","v135","v136","v137","v138","v139", \
  "v140","v141","v142","v143","v144","v145","v146","v147","v148","v149", \
  "v150","v151","v152","v153","v154","v155","v156","v157","v158","v159", \
  "v160","v161","v162","v163","v164","v165","v166","v167","v168","v169", \
  "v170","v171","v172","v173","v174","v175","v176","v177","v178","v179", \
  "v180","v181","v182","v183","v184","v185","v186","v187","v188","v189", \
  "v190","v191","v192","v193","v194","v195","v196","v197","v198","v199", \
  "v200","v201","v202","v203","v204","v205","v206","v207","v208","v209", \
  "v210","v211","v212","v213","v214","v215","v216","v217","v218","v219", \
  "v220","v221","v222","v223","v224","v225","v226","v227","v228","v229", \
  "v230","v231","v232","v233","v234","v235","v236","v237","v238","v239", \
  "v240","v241","v242","v243","v244","v245","v246","v247","v248","v249", \
  "v250","v251"

// h-broadcast scratch pairs v[80:81]..v[98:99].
#define HCLOB \
  "v80","v81","v82","v83","v84","v85","v86","v87","v88","v89", \
  "v90","v91","v92","v93","v94","v95","v96","v97","v98","v99"

// Load one k-slot (slot m at byte offset 32*m) for all 8 rows.
#define LD8(a0,a1,b0,b1,c0,c1,d0,d1,OFF) \
  "global_load_dword v" #a0 ", %[p0], off offset:" #OFF "\n\t" \
  "global_load_dword v" #a1 ", %[p1], off offset:" #OFF "\n\t" \
  "global_load_dword v" #b0 ", %[p2], off offset:" #OFF "\n\t" \
  "global_load_dword v" #b1 ", %[p3], off offset:" #OFF "\n\t" \
  "global_load_dword v" #c0 ", %[p4], off offset:" #OFF "\n\t" \
  "global_load_dword v" #c1 ", %[p5], off offset:" #OFF "\n\t" \
  "global_load_dword v" #d0 ", %[p6], off offset:" #OFF "\n\t" \
  "global_load_dword v" #d1 ", %[p7], off offset:" #OFF "\n\t"

// pk_fma / pk_mul with broadcast from LOW or HIGH word of VGPR pair hp.
#define PKBL(hp, wp, acc) \
  "v_pk_fma_f32 " acc ", " hp ", " wp ", " acc " op_sel:[0,0,0] op_sel_hi:[0,1,1]\n\t"
#define PKBH(hp, wp, acc) \
  "v_pk_fma_f32 " acc ", " hp ", " wp ", " acc " op_sel:[1,0,0] op_sel_hi:[1,1,1]\n\t"
#define PKML(hp, wp, acc) \
  "v_pk_mul_f32 " acc ", " hp ", " wp " op_sel:[0,0] op_sel_hi:[0,1]\n\t"

// One k-slot = 4 chains. S0 = first touch (pk_mul), SL = low word,
// SH = high word of the h pair.
#define S0(P, A,B,C,D) \
  PKML(P, A, "%[a01]") PKML(P, B, "%[a23]") \
  PKML(P, C, "%[a45]") PKML(P, D, "%[a67]")
#define SL(P, A,B,C,D) \
  PKBL(P, A, "%[a01]") PKBL(P, B, "%[a23]") \
  PKBL(P, C, "%[a45]") PKBL(P, D, "%[a67]")
#define SH(P, A,B,C,D) \
  PKBH(P, A, "%[a01]") PKBH(P, B, "%[a23]") \
  PKBH(P, C, "%[a45]") PKBH(P, D, "%[a67]")

__global__ __launch_bounds__(512, 2) void gru_seq_kernel(
    const float* __restrict__ input,   // [B,T]
    const float* __restrict__ W_ih,    // [450,1]
    const float* __restrict__ W_hh,    // [450,150]
    const float* __restrict__ b_ih,    // [450]
    const float* __restrict__ b_hh,    // [450]
    const float* __restrict__ W_lin,   // [1,150]
    const float* __restrict__ b_lin,   // [1]
    float* __restrict__ out)           // [B,T]
{
    const int b    = blockIdx.x;
    const int tid  = threadIdx.x;
    const int lane = tid & 63;
    const int wid  = tid >> 6;               // 0..7 = chain (k mod 8)

    __shared__ float xrow[TT];         // 8 KB input row
    __shared__ float PPf[4352];        // 17.4 KB partials:
                                       // float2-idx = w*272 + p*68 + lane
    __shared__ __align__(16) float hb[640];  // h: hb[(u&7)*72 + (u>>3)]
    __shared__ float yout[TT];         // 8 KB y buffer

    // ---- prologue -------------------------------------------------------
    ((float4*)xrow)[tid] = ((const float4*)(input + (size_t)b * TT))[tid];
    hb[tid] = 0.f;                     // 0..511
    if (tid < 128) hb[512 + tid] = 0.f;

    // Rows 8*lane..8*lane+7. Row 450 = W_lin (y-row). Row >=451: clamp to
    // 449 (junk partials stored but never read).
    const int r0 = 8 * lane;
#define ROWP(r) ((r) == H3 ? W_lin : W_hh + ((r) < H3 ? (r) : (H3 - 1)) * HH)
    const float* p0 = ROWP(r0)     + wid;   // chain w: element k = 8m+w
    const float* p1 = ROWP(r0 + 1) + wid;
    const float* p2 = ROWP(r0 + 2) + wid;
    const float* p3 = ROWP(r0 + 3) + wid;
    const float* p4 = ROWP(r0 + 4) + wid;
    const float* p5 = ROWP(r0 + 5) + wid;
    const float* p6 = ROWP(r0 + 6) + wid;
    const float* p7 = ROWP(r0 + 7) + wid;

    // m = 0..17 into explicit regs, slot m at byte offset 32*m. Pair-sets
    // (even-aligned): A rows (j0,j1) = v[100+2m], B (j2,j3) = v[138+2m],
    // C (j4,j5) = v[176+2m], D (j6,j7) = v[214+2m].
    asm volatile(
        LD8(100,101,138,139,176,177,214,215, 0)
        LD8(102,103,140,141,178,179,216,217, 32)
        LD8(104,105,142,143,180,181,218,219, 64)
        LD8(106,107,144,145,182,183,220,221, 96)
        LD8(108,109,146,147,184,185,222,223, 128)
        LD8(110,111,148,149,186,187,224,225, 160)
        LD8(112,113,150,151,188,189,226,227, 192)
        LD8(114,115,152,153,190,191,228,229, 224)
        LD8(116,117,154,155,192,193,230,231, 256)
        LD8(118,119,156,157,194,195,232,233, 288)
        LD8(120,121,158,159,196,197,234,235, 320)
        LD8(122,123,160,161,198,199,236,237, 352)
        LD8(124,125,162,163,200,201,238,239, 384)
        LD8(126,127,164,165,202,203,240,241, 416)
        LD8(128,129,166,167,204,205,242,243, 448)
        LD8(130,131,168,169,206,207,244,245, 480)
        LD8(132,133,170,171,208,209,246,247, 512)
        LD8(134,135,172,173,210,211,248,249, 544)
        "s_waitcnt vmcnt(0)\n\t"
        :
        : [p0] "v"(p0), [p1] "v"(p1), [p2] "v"(p2), [p3] "v"(p3),
          [p4] "v"(p4), [p5] "v"(p5), [p6] "v"(p6), [p7] "v"(p7)
        : WCLOB, "memory");
    // m = 18: k = 144+wid. Real for wid<6; for wid>=6 h[150..151]=0 forever
    // (hb slots never written), so load in-bounds junk (k=136+wid).
    {
        const int t18 = (wid < 6) ? 144 : 136;
        float w0 = p0[t18], w1 = p1[t18], w2 = p2[t18], w3 = p3[t18];
        float w4 = p4[t18], w5 = p5[t18], w6 = p6[t18], w7 = p7[t18];
        asm volatile(
            "v_mov_b32 v136, %0\n\tv_mov_b32 v137, %1\n\t"
            "v_mov_b32 v174, %2\n\tv_mov_b32 v175, %3\n\t"
            "v_mov_b32 v212, %4\n\tv_mov_b32 v213, %5\n\t"
            "v_mov_b32 v250, %6\n\tv_mov_b32 v251, %7\n\t"
            :: "v"(w0), "v"(w1), "v"(w2), "v"(w3),
               "v"(w4), "v"(w5), "v"(w6), "v"(w7)
            : "v136","v137","v174","v175","v212","v213","v250","v251");
    }

    // Phase-2 constants (threads 0..149) -- gate math per R24 (rcp).
    float wih_r = 0.f, wih_z = 0.f, wih_n = 0.f;
    float bih_r = 0.f, bih_z = 0.f, bih_n = 0.f;
    float bhh_r = 0.f, bhh_z = 0.f, bhh_n = 0.f;
    if (tid < HH) {
        wih_r = W_ih[tid];          bih_r = b_ih[tid];          bhh_r = b_hh[tid];
        wih_z = W_ih[HH + tid];     bih_z = b_ih[HH + tid];     bhh_z = b_hh[HH + tid];
        wih_n = W_ih[2 * HH + tid]; bih_n = b_ih[2 * HH + tid]; bhh_n = b_hh[2 * HH + tid];
    }
    const float blin = b_lin[0];
    float hreg = 0.f;
    float* outb = out + (size_t)b * TT;
    // Store pointer: 4 float2 (8B lane stride = 2-way alias = free).
    float2* st = (float2*)PPf + wid * 272 + lane;
    // Wave-uniform LDS byte address of this wave's h chain (hb + wid*288).
    const unsigned hva = (unsigned)(size_t)(&hb[wid * 72]);
    // Phase-2 read indices: row r -> float idx (((r&7)>>1)*68 + (r>>3))*2
    // + (r&1); chain offset +544 floats each. 2-way bank alias (free).
    int ir = 0, iz = 0, in_ = 0;
    if (tid < HH) {
        int r;
        r = tid;        ir  = (((r & 7) >> 1) * 68 + (r >> 3)) * 2 + (r & 1);
        r = HH + tid;   iz  = (((r & 7) >> 1) * 68 + (r >> 3)) * 2 + (r & 1);
        r = 2*HH + tid; in_ = (((r & 7) >> 1) * 68 + (r >> 3)) * 2 + (r & 1);
    }
    const int iy = (1 * 68 + 56) * 2;   // row 450: p=1, g=56, c=0 -> 248

    __syncthreads();

    // ---- recurrence -----------------------------------------------------
    // Iteration t dots h_{t-1}; row 450 gives y_{t-1}. Extra iteration
    // t==TT supplies y_{TT-1}; its h-update is guarded off.
    for (int t = 0; t <= TT; ++t) {
        // phase 1: chain w of rows 8l..8l+7. h broadcasts arrive via 10
        // uniform-address ds_read_b64, pipelined under MACs (counted
        // lgkmcnt, tail-robust).
        fx2 a01, a23, a45, a67;        // first-touched by PKML in slot 0
        asm volatile(
            "ds_read_b64 v[80:81], %[va] offset:0\n\t"
            "ds_read_b64 v[82:83], %[va] offset:8\n\t"
            "ds_read_b64 v[84:85], %[va] offset:16\n\t"
            "ds_read_b64 v[86:87], %[va] offset:24\n\t"
            "ds_read_b64 v[88:89], %[va] offset:32\n\t"
            "ds_read_b64 v[90:91], %[va] offset:40\n\t"
            "ds_read_b64 v[92:93], %[va] offset:48\n\t"
            "ds_read_b64 v[94:95], %[va] offset:56\n\t"
            "ds_read_b64 v[96:97], %[va] offset:64\n\t"
            "ds_read_b64 v[98:99], %[va] offset:72\n\t"
            "s_waitcnt lgkmcnt(8)\n\t"   // pairs 0,1 landed (tail-robust)
            S0("v[80:81]", "v[100:101]","v[138:139]","v[176:177]","v[214:215]")
            SH("v[80:81]", "v[102:103]","v[140:141]","v[178:179]","v[216:217]")
            SL("v[82:83]", "v[104:105]","v[142:143]","v[180:181]","v[218:219]")
            SH("v[82:83]", "v[106:107]","v[144:145]","v[182:183]","v[220:221]")
            "s_waitcnt lgkmcnt(6)\n\t"   // pairs 2,3
            SL("v[84:85]", "v[108:109]","v[146:147]","v[184:185]","v[222:223]")
            SH("v[84:85]", "v[110:111]","v[148:149]","v[186:187]","v[224:225]")
            SL("v[86:87]", "v[112:113]","v[150:151]","v[188:189]","v[226:227]")
            SH("v[86:87]", "v[114:115]","v[152:153]","v[190:191]","v[228:229]")
            "s_waitcnt lgkmcnt(4)\n\t"   // pairs 4,5
            SL("v[88:89]", "v[116:117]","v[154:155]","v[192:193]","v[230:231]")
            SH("v[88:89]", "v[118:119]","v[156:157]","v[194:195]","v[232:233]")
            SL("v[90:91]", "v[120:121]","v[158:159]","v[196:197]","v[234:235]")
            SH("v[90:91]", "v[122:123]","v[160:161]","v[198:199]","v[236:237]")
            "s_waitcnt lgkmcnt(2)\n\t"   // pairs 6,7
            SL("v[92:93]", "v[124:125]","v[162:163]","v[200:201]","v[238:239]")
            SH("v[92:93]", "v[126:127]","v[164:165]","v[202:203]","v[240:241]")
            SL("v[94:95]", "v[128:129]","v[166:167]","v[204:205]","v[242:243]")
            SH("v[94:95]", "v[130:131]","v[168:169]","v[206:207]","v[244:245]")
            "s_waitcnt lgkmcnt(0)\n\t"   // pairs 8,9
            SL("v[96:97]", "v[132:133]","v[170:171]","v[208:209]","v[246:247]")
            SH("v[96:97]", "v[134:135]","v[172:173]","v[210:211]","v[248:249]")
            SL("v[98:99]", "v[136:137]","v[174:175]","v[212:213]","v[250:251]")
            : [a01] "=&v"(a01), [a23] "=&v"(a23),
              [a45] "=&v"(a45), [a67] "=&v"(a67)
            : [va] "v"(hva)
            : HCLOB, WCLOB);
        // Four conflict-free b64 stores (8B lane stride).
        float2 s01; s01.x = a01.x; s01.y = a01.y;
        float2 s23; s23.x = a23.x; s23.y = a23.y;
        float2 s45; s45.x = a45.x; s45.y = a45.y;
        float2 s67; s67.x = a67.x; s67.y = a67.y;
        st[0]   = s01;
        st[68]  = s23;
        st[136] = s45;
        st[204] = s67;
        __syncthreads();

        // phase 2: gates + hidden update (threads 0..149), skipped at t==TT.
        // pre_row = (((c0+c1)+(c2+c3)) + ((c4+c5)+(c6+c7))) + bhh.
        // Divides replaced by v_rcp_f32 (1-ulp) + mul: r,z,n.
        if (t < TT && tid < HH) {
            float x  = xrow[t];
            float pr = (((PPf[ir]         + PPf[ir + 544])
                       + (PPf[ir + 1088]  + PPf[ir + 1632]))
                      + ((PPf[ir + 2176]  + PPf[ir + 2720])
                       + (PPf[ir + 3264]  + PPf[ir + 3808]))) + bhh_r;
            float pz = (((PPf[iz]         + PPf[iz + 544])
                       + (PPf[iz + 1088]  + PPf[iz + 1632]))
                      + ((PPf[iz + 2176]  + PPf[iz + 2720])
                       + (PPf[iz + 3264]  + PPf[iz + 3808]))) + bhh_z;
            float pn = (((PPf[in_]        + PPf[in_ + 544])
                       + (PPf[in_ + 1088] + PPf[in_ + 1632]))
                      + ((PPf[in_ + 2176] + PPf[in_ + 2720])
                       + (PPf[in_ + 3264] + PPf[in_ + 3808]))) + bhh_n;
            float gr = fmaf(x, wih_r, bih_r) + pr;
            float gz = fmaf(x, wih_z, bih_z) + pz;
            float r  = __builtin_amdgcn_rcpf(1.f + __expf(-gr));
            float z  = __builtin_amdgcn_rcpf(1.f + __expf(-gz));
            float ta = fmaf(x, wih_n, bih_n) + r * pn;
            ta = fminf(fmaxf(ta, -15.f), 15.f);
            float e  = __expf(2.f * ta);
            float n  = (e - 1.f) * __builtin_amdgcn_rcpf(e + 1.f);  // tanh
            float hnew = fmaf(z, hreg - n, n);       // (1-z)*n + z*h
            hnew = fmaxf(hnew, 0.f);                 // relu
            hreg = hnew;
            hb[(tid & 7) * 72 + (tid >> 3)] = hnew;  // 2-way write alias
        }
        // y_{t-1} from phase-1 row 450 (same 8-term tree), wave 7.
        if (t > 0 && tid == H3) {
            yout[t - 1] = (((PPf[iy]        + PPf[iy + 544])
                          + (PPf[iy + 1088] + PPf[iy + 1632]))
                         + ((PPf[iy + 2176] + PPf[iy + 2720])
                          + (PPf[iy + 3264] + PPf[iy + 3808]))) + blin;
        }
        __syncthreads();
    }

    // ---- epilogue: coalesced y dump (the loop's only global write) -------
    ((float4*)outb)[tid] = ((const float4*)yout)[tid];
}

extern "C" void kernel_launch(void* const* d_in, const int* in_sizes, int n_in,
                              void* d_out, int out_size, void* d_ws, size_t ws_size,
                              hipStream_t stream) {
    const float* input = (const float*)d_in[0];
    const float* W_ih  = (const float*)d_in[1];
    const float* W_hh  = (const float*)d_in[2];
    const float* b_ih  = (const float*)d_in[3];
    const float* b_hh  = (const float*)d_in[4];
    const float* W_lin = (const float*)d_in[5];
    const float* b_lin = (const float*)d_in[6];
    float* out = (float*)d_out;

    gru_seq_kernel<<<dim3(BB), dim3(512), 0, stream>>>(
        input, W_ih, W_hh, b_ih, b_hh, W_lin, b_lin, out);
}